// Round 10
// baseline (134.952 us; speedup 1.0000x reference)
//
#include <hip/hip_runtime.h>
#include <hip/hip_bf16.h>

// ---------- types ----------
typedef __attribute__((ext_vector_type(8))) __bf16 bf16x8;
typedef __attribute__((ext_vector_type(4))) float f32x4;

__device__ __forceinline__ unsigned short f2bf(float f) {
    unsigned int u = __float_as_uint(f);
    unsigned int r = u + 0x7FFFu + ((u >> 16) & 1u);   // RNE
    return (unsigned short)(r >> 16);
}

__device__ __forceinline__ void async_copy16(const unsigned short* g, unsigned short* l) {
    __builtin_amdgcn_global_load_lds(
        (__attribute__((address_space(1))) void*)(g),
        (__attribute__((address_space(3))) void*)(l), 16, 0, 0);
}

// ---------- kernel: fp32 -> bf16 (8 elems/thread), proven R1/R2 version ----------
__global__ __launch_bounds__(256) void cvt_f32_bf16(const float4* __restrict__ in,
                                                    uint4* __restrict__ out, int n8) {
    int i = blockIdx.x * blockDim.x + threadIdx.x;
    if (i >= n8) return;
    float4 a = in[2 * i], b = in[2 * i + 1];
    union { unsigned short s[8]; uint4 v; } r;
    r.s[0] = f2bf(a.x); r.s[1] = f2bf(a.y); r.s[2] = f2bf(a.z); r.s[3] = f2bf(a.w);
    r.s[4] = f2bf(b.x); r.s[5] = f2bf(b.y); r.s[6] = f2bf(b.z); r.s[7] = f2bf(b.w);
    out[i] = r.v;
}

// ---------- transpose + cvt: in[R][C] f32 -> out[C][R] bf16 ----------
__global__ __launch_bounds__(256) void transpose_cvt(const float* __restrict__ in,
                                                     unsigned short* __restrict__ out,
                                                     int R, int C) {
    __shared__ float tile[32][33];
    int c0 = blockIdx.x * 32, r0 = blockIdx.y * 32;
    int tx = threadIdx.x, ty = threadIdx.y;          // block (32,8)
    #pragma unroll
    for (int i = 0; i < 32; i += 8)
        tile[ty + i][tx] = in[(size_t)(r0 + ty + i) * C + c0 + tx];
    __syncthreads();
    #pragma unroll
    for (int i = 0; i < 32; i += 8)
        out[(size_t)(c0 + ty + i) * R + r0 + tx] = f2bf(tile[tx][ty + i]);
}

// ---------- phased 256x128 bf16 GEMM core ----------
// 512 thr / 8 waves (4M x 2N, 64x64 per wave). BK=64, K=512 (8 K-tiles).
// Double-buffered LDS; per K-tile: 4 quadrant-phases, each issuing 1-2
// global_load_lds units of tile kt+1 into slot^1 (never read this K-tile),
// then 8 ds_read_b128 + 8 MFMA from the read slot. NO intra-tile barriers
// (read slot is read-only; write slot untouched by readers). ONE
// __syncthreads() per K-tile: its implicit vmcnt(0) drains the kt+1 loads
// AFTER ~4 phases of compute cover; nothing else is in flight at that point.
__device__ __forceinline__ void gemm_core_ph(const unsigned short* __restrict__ A,
                                             const unsigned short* __restrict__ Bt,
                                             int m0, int n0, f32x4 acc[4][4]) {
    constexpr int K = 512, NT = 8;
    __shared__ unsigned short As[2][256 * 64];   // 64 KiB
    __shared__ unsigned short Bs[2][128 * 64];   // 32 KiB

    const int tid  = (int)threadIdx.x;
    const int lane = tid & 63;
    const int wv   = tid >> 6;                   // 0..7
    const int wr   = wv >> 1, wc = wv & 1;       // 4M x 2N
    const int l15  = lane & 15, l16 = lane >> 4;

    const int r64 = tid >> 3;                    // staging row [0,64)
    const int kc  = (tid & 7) * 8;               // staging col (8 bf16 = 16B)

    f32x4 zz = {0.f, 0.f, 0.f, 0.f};
    #pragma unroll
    for (int i = 0; i < 4; ++i)
        #pragma unroll
        for (int j = 0; j < 4; ++j) acc[i][j] = zz;

    // prologue: stage K-tile 0 -> slot 0 (6 units), full drain once
    #pragma unroll
    for (int u = 0; u < 4; ++u)
        async_copy16(A + (size_t)(m0 + u * 64 + r64) * K + kc,
                     As[0] + (u * 64 + r64) * 64 + kc);
    #pragma unroll
    for (int u = 0; u < 2; ++u)
        async_copy16(Bt + (size_t)(n0 + u * 64 + r64) * K + kc,
                     Bs[0] + (u * 64 + r64) * 64 + kc);
    __syncthreads();

    for (int kt = 0; kt < NT; ++kt) {
        const int slot = kt & 1;
        const unsigned short* Ar = As[slot];
        const unsigned short* Br = Bs[slot];
        unsigned short* Aw = As[slot ^ 1];
        unsigned short* Bw = Bs[slot ^ 1];
        const int k1 = (kt + 1) * 64;
        const bool more = (kt + 1 < NT);

        #pragma unroll
        for (int q = 0; q < 4; ++q) {
            // stage one chunk of K-tile kt+1 into the write slot
            if (more) {
                if (q == 0) {
                    async_copy16(A + (size_t)(m0 + 0 * 64 + r64) * K + k1 + kc, Aw + (0 * 64 + r64) * 64 + kc);
                    async_copy16(A + (size_t)(m0 + 1 * 64 + r64) * K + k1 + kc, Aw + (1 * 64 + r64) * 64 + kc);
                } else if (q == 1) {
                    async_copy16(A + (size_t)(m0 + 2 * 64 + r64) * K + k1 + kc, Aw + (2 * 64 + r64) * 64 + kc);
                    async_copy16(A + (size_t)(m0 + 3 * 64 + r64) * K + k1 + kc, Aw + (3 * 64 + r64) * 64 + kc);
                } else if (q == 2) {
                    async_copy16(Bt + (size_t)(n0 + 0 * 64 + r64) * K + k1 + kc, Bw + (0 * 64 + r64) * 64 + kc);
                } else {
                    async_copy16(Bt + (size_t)(n0 + 1 * 64 + r64) * K + k1 + kc, Bw + (1 * 64 + r64) * 64 + kc);
                }
            }
            const int qm = q >> 1, qn = q & 1;
            bf16x8 a[2][2], b[2][2];
            #pragma unroll
            for (int i = 0; i < 2; ++i)
                #pragma unroll
                for (int kk = 0; kk < 2; ++kk)
                    a[i][kk] = *(const bf16x8*)(const void*)(Ar + (wr * 64 + (qm * 2 + i) * 16 + l15) * 64 + kk * 32 + l16 * 8);
            #pragma unroll
            for (int j = 0; j < 2; ++j)
                #pragma unroll
                for (int kk = 0; kk < 2; ++kk)
                    b[j][kk] = *(const bf16x8*)(const void*)(Br + (wc * 64 + (qn * 2 + j) * 16 + l15) * 64 + kk * 32 + l16 * 8);
            __builtin_amdgcn_s_setprio(1);
            #pragma unroll
            for (int kk = 0; kk < 2; ++kk)
                #pragma unroll
                for (int i = 0; i < 2; ++i)
                    #pragma unroll
                    for (int j = 0; j < 2; ++j)
                        acc[qm * 2 + i][qn * 2 + j] =
                            __builtin_amdgcn_mfma_f32_16x16x32_bf16(a[i][kk], b[j][kk],
                                                                    acc[qm * 2 + i][qn * 2 + j], 0, 0, 0);
            __builtin_amdgcn_s_setprio(0);
        }
        __syncthreads();   // drains kt+1 stage loads (covered by 4 phases) + read-slot handoff
    }
}

// ---------- QKV GEMM: phased core + Q/K/V scatter epilogue ----------
// Grid 768 = 64 M-tiles(256) x 12 N-tiles(128) = 3 full CU-rounds.
__global__ __launch_bounds__(512) void gemm_qkv_ph(const unsigned short* __restrict__ xb,
                                                   const unsigned short* __restrict__ wT,
                                                   unsigned short* __restrict__ Qb,
                                                   unsigned short* __restrict__ Kb,
                                                   unsigned short* __restrict__ Vb) {
    const int bid = blockIdx.x;
    const int xcd = bid & 7, idx = bid >> 3;        // 768 % 8 == 0 -> bijective
    const int mt  = xcd * 8 + idx / 12;             // 64 M-tiles, 8 per XCD chunk
    const int nt  = idx % 12;
    const int m0 = mt * 256, n0 = nt * 128;

    f32x4 acc[4][4];
    gemm_core_ph(xb, wT, m0, n0, acc);

    const int lane = (int)threadIdx.x & 63, wv = (int)threadIdx.x >> 6;
    const int wr = wv >> 1, wc = wv & 1;
    const int l15 = lane & 15, l16 = lane >> 4;
    #pragma unroll
    for (int j = 0; j < 4; ++j) {
        int col = n0 + wc * 64 + j * 16 + l15;
        int t = col >> 9;                      // 0=Q 1=K 2=V (uniform per block: 512%128==0)
        int within = col & 511;
        int h = within >> 6, d = within & 63;
        unsigned short* dst = (t == 0) ? Qb : (t == 1) ? Kb : Vb;
        float scl = (t == 0) ? 0.125f : 1.0f;  // SCALE = 64^-0.5 folded into Q
        #pragma unroll
        for (int i = 0; i < 4; ++i)
            #pragma unroll
            for (int e = 0; e < 4; ++e) {
                int row = m0 + wr * 64 + i * 16 + (l16 << 2) + e;
                int b = row >> 9, n = row & 511;
                dst[(((size_t)b * 8 + h) * 512 + n) * 64 + d] = f2bf(acc[i][j][e] * scl);
            }
    }
}

// ---------- projection GEMM: phased core + bias epilogue -> fp32 out ----------
// Grid 256 = 64 M-tiles x 4 N-tiles = exactly 1 CU-round.
__global__ __launch_bounds__(512) void gemm_proj_ph(const unsigned short* __restrict__ Ab,
                                                    const unsigned short* __restrict__ wT,
                                                    const float* __restrict__ bias,
                                                    float* __restrict__ out) {
    const int bid = blockIdx.x;
    const int xcd = bid & 7, idx = bid >> 3;        // 256 % 8 == 0
    const int mt  = xcd * 8 + idx / 4;
    const int nt  = idx % 4;
    const int m0 = mt * 256, n0 = nt * 128;

    f32x4 acc[4][4];
    gemm_core_ph(Ab, wT, m0, n0, acc);

    const int lane = (int)threadIdx.x & 63, wv = (int)threadIdx.x >> 6;
    const int wr = wv >> 1, wc = wv & 1;
    const int l15 = lane & 15, l16 = lane >> 4;
    #pragma unroll
    for (int j = 0; j < 4; ++j) {
        int col = n0 + wc * 64 + j * 16 + l15;
        float bb = bias[col];
        #pragma unroll
        for (int i = 0; i < 4; ++i)
            #pragma unroll
            for (int e = 0; e < 4; ++e) {
                int row = m0 + wr * 64 + i * 16 + (l16 << 2) + e;
                out[(size_t)row * 512 + col] = acc[i][j][e] + bb;
            }
    }
}

// ---------- local-window flash attention (swapped-QK^T, 64-key half-tiles) ----------
// grid = 256 bh * 4 qtiles; block = 4 waves; each wave owns 32 q rows (one qh, half the w's).
__global__ __launch_bounds__(256, 4) void attn_kernel(const unsigned short* __restrict__ Qb,
                                                      const unsigned short* __restrict__ Kb,
                                                      const unsigned short* __restrict__ Vb,
                                                      unsigned short* __restrict__ Ob) {
    __shared__ unsigned short Ks[64 * 72];        // [key within half][d] pad to 72
    __shared__ unsigned short Vt[64 * 72];        // [d][key within half] pad to 72
    __shared__ unsigned short Ps[4 * 32 * 72];    // per-wave P tile [32 q][64 key] pad to 72

    const int bh = blockIdx.x >> 2;
    const int qt = blockIdx.x & 3;
    const int tid = threadIdx.x;
    const int lane = tid & 63;
    const int wv = tid >> 6;
    const int l15 = lane & 15, l16 = lane >> 4;
    const int b = bh >> 3, h = bh & 7;

    const unsigned short* Qp = Qb + (size_t)bh * 512 * 64;
    const unsigned short* Kp = Kb + (size_t)bh * 512 * 64;
    const unsigned short* Vp = Vb + (size_t)bh * 512 * 64;
    unsigned short* Pw = Ps + wv * 32 * 72;

    const int qrow0 = qt * 128 + wv * 32;
    const int qh = qrow0 >> 6;           // uniform per wave
    const int wq0 = qrow0 & 63;          // 0 or 32, uniform per wave
    const int dead_g = wq0 ? 0 : 3;      // fully-w-masked 16-key group per wave

    // per-lane w-mask bits: bit(qf*16 + g*4 + j) = |qw - kw| <= 5
    unsigned int wbits = 0;
    {
        int qw[2] = { wq0 + l15, wq0 + 16 + l15 };
        #pragma unroll
        for (int qf = 0; qf < 2; ++qf)
            #pragma unroll
            for (int g = 0; g < 4; ++g)
                #pragma unroll
                for (int j = 0; j < 4; ++j) {
                    int kw = g * 16 + (l16 << 2) + j;
                    int dw = qw[qf] - kw; dw = dw < 0 ? -dw : dw;
                    wbits |= (dw <= 5 ? 1u : 0u) << (qf * 16 + g * 4 + j);
                }
    }

    // Q B-fragments (q = qf*16+l15, k-contiguous) in registers; pre-scaled by SCALE
    bf16x8 bQ[2][2];
    #pragma unroll
    for (int qf = 0; qf < 2; ++qf)
        #pragma unroll
        for (int kf = 0; kf < 2; ++kf)
            bQ[qf][kf] = *(const bf16x8*)(const void*)(Qp + (size_t)(qrow0 + qf * 16 + l15) * 64 + kf * 32 + l16 * 8);

    f32x4 o[2][4];
    f32x4 zz = {0.f, 0.f, 0.f, 0.f};
    float mrow[2] = {-INFINITY, -INFINITY}, lrow[2] = {0.f, 0.f};
    #pragma unroll
    for (int qf = 0; qf < 2; ++qf)
        #pragma unroll
        for (int df = 0; df < 4; ++df) o[qf][df] = zz;

    for (int kh = 0; kh < 8; ++kh) {
        // block-level skip (uniform): kh in [2qt-3, 2qt+4]
        int dlo = kh - 2 * qt;
        if (dlo < -3 || dlo > 4) continue;
        __syncthreads();
        // stage K half-tile [64 keys][64 d] (vector LDS stores)
        #pragma unroll
        for (int c = 0; c < 2; ++c) {
            int flat16 = c * 256 + tid;
            int key = flat16 >> 3, dk = (flat16 & 7) * 8;
            *(uint4*)(void*)(Ks + key * 72 + dk) = *(const uint4*)(const void*)(Kp + ((size_t)(kh * 64 + key) * 64 + dk));
        }
        // stage V transposed: Vt[d][key]
        #pragma unroll
        for (int c = 0; c < 2; ++c) {
            int flat16 = c * 256 + tid;
            int key = flat16 & 63, d8 = flat16 >> 6;     // d8 in [0,8)
            union { uint4 v; unsigned short s[8]; } t;
            t.v = *(const uint4*)(const void*)(Vp + ((size_t)(kh * 64 + key) * 64 + d8 * 8));
            #pragma unroll
            for (int e = 0; e < 8; ++e) Vt[(d8 * 8 + e) * 72 + key] = t.s[e];
        }
        __syncthreads();

        int adq = qh - kh; adq = adq < 0 ? -adq : adq;
        if (adq > 3) continue;           // wave-uniform skip; no barriers below

        // S^T = K . Q^T : D[key = g*16 + l16*4 + j][q = qf*16 + l15]
        f32x4 s[2][4];
        #pragma unroll
        for (int qf = 0; qf < 2; ++qf)
            #pragma unroll
            for (int g = 0; g < 4; ++g) s[qf][g] = zz;
        #pragma unroll
        for (int g = 0; g < 4; ++g) {
            if (g == dead_g) continue;   // wave-uniform
            bf16x8 aK0 = *(const bf16x8*)(const void*)(Ks + (g * 16 + l15) * 72 + 0  + l16 * 8);
            bf16x8 aK1 = *(const bf16x8*)(const void*)(Ks + (g * 16 + l15) * 72 + 32 + l16 * 8);
            #pragma unroll
            for (int qf = 0; qf < 2; ++qf) {
                s[qf][g] = __builtin_amdgcn_mfma_f32_16x16x32_bf16(aK0, bQ[qf][0], s[qf][g], 0, 0, 0);
                s[qf][g] = __builtin_amdgcn_mfma_f32_16x16x32_bf16(aK1, bQ[qf][1], s[qf][g], 0, 0, 0);
            }
        }

        // w-mask + per-q running max (q is lane-local: q = qf*16+l15)
        float tmax[2] = {-1e30f, -1e30f};
        #pragma unroll
        for (int qf = 0; qf < 2; ++qf) {
            #pragma unroll
            for (int g = 0; g < 4; ++g) {
                if (g == dead_g) continue;
                #pragma unroll
                for (int j = 0; j < 4; ++j) {
                    float v = ((wbits >> (qf * 16 + g * 4 + j)) & 1u) ? s[qf][g][j] : -1e30f;
                    s[qf][g][j] = v;
                    tmax[qf] = fmaxf(tmax[qf], v);
                }
            }
            float t = tmax[qf];
            t = fmaxf(t, __shfl_xor(t, 16));
            t = fmaxf(t, __shfl_xor(t, 32));
            tmax[qf] = t;
        }

        // online-softmax update + O rescale (o rows live at q = qf*16 + l16*4 + j)
        #pragma unroll
        for (int qf = 0; qf < 2; ++qf) {
            float mnew = fmaxf(mrow[qf], tmax[qf]);
            float fs = __expf(mrow[qf] - mnew);
            mrow[qf] = mnew;
            lrow[qf] *= fs;
            #pragma unroll
            for (int j = 0; j < 4; ++j) {
                float fso = __shfl(fs, (l16 << 2) + j);
                #pragma unroll
                for (int df = 0; df < 4; ++df) o[qf][df][j] *= fso;
            }
        }

        // P = exp(S - m): pack pairs to bf16, b64 write into per-wave LDS; row sums
        #pragma unroll
        for (int qf = 0; qf < 2; ++qf) {
            float lsum = 0.f;
            #pragma unroll
            for (int g = 0; g < 4; ++g) {
                unsigned int lo, hi;
                if (g == dead_g) {
                    lo = 0u; hi = 0u;
                } else {
                    float e0 = __expf(s[qf][g][0] - mrow[qf]);
                    float e1 = __expf(s[qf][g][1] - mrow[qf]);
                    float e2 = __expf(s[qf][g][2] - mrow[qf]);
                    float e3 = __expf(s[qf][g][3] - mrow[qf]);
                    lsum += (e0 + e1) + (e2 + e3);
                    asm("v_cvt_pk_bf16_f32 %0, %1, %2" : "=v"(lo) : "v"(e0), "v"(e1));
                    asm("v_cvt_pk_bf16_f32 %0, %1, %2" : "=v"(hi) : "v"(e2), "v"(e3));
                }
                uint2 w; w.x = lo; w.y = hi;
                *(uint2*)(void*)(Pw + (qf * 16 + l15) * 72 + g * 16 + (l16 << 2)) = w;
            }
            float t = lsum;
            t += __shfl_xor(t, 16);
            t += __shfl_xor(t, 32);
            lrow[qf] += t;
        }
        asm volatile("" ::: "memory");   // order P writes before fragment reads (same wave, DS in-order)

        // O += P V  (A = P[q][k], B = V^T[d][k])
        #pragma unroll
        for (int kf = 0; kf < 2; ++kf) {
            bf16x8 aP0 = *(const bf16x8*)(const void*)(Pw + (0 * 16 + l15) * 72 + kf * 32 + l16 * 8);
            bf16x8 aP1 = *(const bf16x8*)(const void*)(Pw + (1 * 16 + l15) * 72 + kf * 32 + l16 * 8);
            #pragma unroll
            for (int df = 0; df < 4; ++df) {
                bf16x8 bV = *(const bf16x8*)(const void*)(Vt + (df * 16 + l15) * 72 + kf * 32 + l16 * 8);
                o[0][df] = __builtin_amdgcn_mfma_f32_16x16x32_bf16(aP0, bV, o[0][df], 0, 0, 0);
                o[1][df] = __builtin_amdgcn_mfma_f32_16x16x32_bf16(aP1, bV, o[1][df], 0, 0, 0);
            }
        }
    }

    // epilogue: O /= l, write bf16 [b][n][h*64+d]; o rows at q = qf*16 + l16*4 + j
    #pragma unroll
    for (int qf = 0; qf < 2; ++qf) {
        float linv = 1.0f / lrow[qf];
        #pragma unroll
        for (int j = 0; j < 4; ++j) {
            float lj = __shfl(linv, (l16 << 2) + j);
            int q = qrow0 + qf * 16 + (l16 << 2) + j;
            size_t base = ((size_t)b * 512 + q) * 512 + h * 64;
            #pragma unroll
            for (int df = 0; df < 4; ++df)
                Ob[base + df * 16 + l15] = f2bf(o[qf][df][j] * lj);
        }
    }
}

// ---------- launch ----------
extern "C" void kernel_launch(void* const* d_in, const int* in_sizes, int n_in,
                              void* d_out, int out_size, void* d_ws, size_t ws_size,
                              hipStream_t stream) {
    const float* x      = (const float*)d_in[0];   // [32,512,512]
    const float* w_qkv  = (const float*)d_in[1];   // [512,1536]
    const float* w_proj = (const float*)d_in[2];   // [512,512]
    const float* b_proj = (const float*)d_in[3];   // [512]
    // d_in[4] (mask) is reproduced analytically in-kernel.
    float* out = (float*)d_out;

    char* ws = (char*)d_ws;
    unsigned short* xb     = (unsigned short*)(ws);                 // 16 MB (reused as Ob)
    unsigned short* wqkvT  = (unsigned short*)(ws + 16777216);      // 1.5 MB
    unsigned short* wprojT = (unsigned short*)(ws + 18350080);      // 0.5 MB
    unsigned short* Qb     = (unsigned short*)(ws + 18874368);      // 16 MB
    unsigned short* Kb     = (unsigned short*)(ws + 35651584);      // 16 MB
    unsigned short* Vb     = (unsigned short*)(ws + 52428800);      // 16 MB
    unsigned short* Ob     = xb;  // xb dead after gemm_qkv_ph; alias for attn output

    cvt_f32_bf16<<<4096, 256, 0, stream>>>((const float4*)x, (uint4*)xb, 1048576);
    transpose_cvt<<<dim3(48, 16), dim3(32, 8), 0, stream>>>(w_qkv, wqkvT, 512, 1536);
    transpose_cvt<<<dim3(16, 16), dim3(32, 8), 0, stream>>>(w_proj, wprojT, 512, 512);
    gemm_qkv_ph<<<768, 512, 0, stream>>>(xb, wqkvT, Qb, Kb, Vb);
    attn_kernel<<<1024, 256, 0, stream>>>(Qb, Kb, Vb, Ob);
    gemm_proj_ph<<<256, 512, 0, stream>>>(Ob, wprojT, b_proj, out);
}

// Round 11
// 101.242 us; speedup vs baseline: 1.3330x; 1.3330x over previous
//
#include <hip/hip_runtime.h>
#include <hip/hip_bf16.h>

// ---------- types ----------
typedef __attribute__((ext_vector_type(8))) __bf16 bf16x8;
typedef __attribute__((ext_vector_type(4))) float f32x4;

__device__ __forceinline__ unsigned short f2bf(float f) {
    unsigned int u = __float_as_uint(f);
    unsigned int r = u + 0x7FFFu + ((u >> 16) & 1u);   // RNE
    return (unsigned short)(r >> 16);
}

__device__ __forceinline__ void async_copy16(const unsigned short* g, unsigned short* l) {
    __builtin_amdgcn_global_load_lds(
        (__attribute__((address_space(1))) void*)(g),
        (__attribute__((address_space(3))) void*)(l), 16, 0, 0);
}

// ---------- kernel 1: fp32 -> bf16 (8 elems/thread) ----------
__global__ __launch_bounds__(256) void cvt_f32_bf16(const float4* __restrict__ in,
                                                    uint4* __restrict__ out, int n8) {
    int i = blockIdx.x * blockDim.x + threadIdx.x;
    if (i >= n8) return;
    float4 a = in[2 * i], b = in[2 * i + 1];
    union { unsigned short s[8]; uint4 v; } r;
    r.s[0] = f2bf(a.x); r.s[1] = f2bf(a.y); r.s[2] = f2bf(a.z); r.s[3] = f2bf(a.w);
    r.s[4] = f2bf(b.x); r.s[5] = f2bf(b.y); r.s[6] = f2bf(b.z); r.s[7] = f2bf(b.w);
    out[i] = r.v;
}

// ---------- kernel 2: transpose + cvt: in[R][C] f32 -> out[C][R] bf16 ----------
__global__ __launch_bounds__(256) void transpose_cvt(const float* __restrict__ in,
                                                     unsigned short* __restrict__ out,
                                                     int R, int C) {
    __shared__ float tile[32][33];
    int c0 = blockIdx.x * 32, r0 = blockIdx.y * 32;
    int tx = threadIdx.x, ty = threadIdx.y;          // block (32,8)
    #pragma unroll
    for (int i = 0; i < 32; i += 8)
        tile[ty + i][tx] = in[(size_t)(r0 + ty + i) * C + c0 + tx];
    __syncthreads();
    #pragma unroll
    for (int i = 0; i < 32; i += 8)
        out[(size_t)(c0 + ty + i) * R + r0 + tx] = f2bf(tile[tx][ty + i]);
}

// ---------- single-buffered 128x128 bf16 GEMM core (R2-proven, byte-identical) ----------
__device__ __forceinline__ void gemm_core_128(const unsigned short* __restrict__ A,
                                              const unsigned short* __restrict__ Bt,
                                              int K, int m0, int n0, f32x4 acc[4][4]) {
    __shared__ unsigned short As[128 * 64];
    __shared__ unsigned short Bs[128 * 64];
    const int lane = threadIdx.x & 63;
    const int wv   = threadIdx.x >> 6;
    const int wm = (wv >> 1) * 64, wn = (wv & 1) * 64;
    const int l15 = lane & 15, l16 = lane >> 4;

    f32x4 zz = {0.f, 0.f, 0.f, 0.f};
    #pragma unroll
    for (int i = 0; i < 4; ++i)
        #pragma unroll
        for (int j = 0; j < 4; ++j) acc[i][j] = zz;

    for (int k0 = 0; k0 < K; k0 += 64) {
        if (k0) __syncthreads();
        #pragma unroll
        for (int c = 0; c < 4; ++c) {
            int flat16 = c * 256 + (int)threadIdx.x;      // one 16B chunk = 8 bf16
            int r  = flat16 >> 3;
            int kk = (flat16 & 7) * 8;
            async_copy16(A  + (size_t)(m0 + r) * K + k0 + kk, As + flat16 * 8);
            async_copy16(Bt + (size_t)(n0 + r) * K + k0 + kk, Bs + flat16 * 8);
        }
        __syncthreads();   // drains vmcnt -> tiles resident
        #pragma unroll
        for (int kk = 0; kk < 64; kk += 32) {
            bf16x8 a[4], b[4];
            #pragma unroll
            for (int i = 0; i < 4; ++i)
                a[i] = *(const bf16x8*)(const void*)(As + (wm + i * 16 + l15) * 64 + kk + l16 * 8);
            #pragma unroll
            for (int i = 0; i < 4; ++i)
                b[i] = *(const bf16x8*)(const void*)(Bs + (wn + i * 16 + l15) * 64 + kk + l16 * 8);
            #pragma unroll
            for (int i = 0; i < 4; ++i)
                #pragma unroll
                for (int j = 0; j < 4; ++j)
                    acc[i][j] = __builtin_amdgcn_mfma_f32_16x16x32_bf16(a[i], b[j], acc[i][j], 0, 0, 0);
        }
    }
}

// ---------- kernel 3: QKV GEMM (R2 core) + bijective XCD-chunked block swizzle ----------
// 1536 blocks = 128 M-tiles x 12 N-tiles; 1536 % 8 == 0 -> each XCD owns
// 16 contiguous M-tiles x all 12 N -> x panel 2 MB/XCD resident in its L2.
__global__ __launch_bounds__(256) void gemm_qkv(const unsigned short* __restrict__ xb,
                                                const unsigned short* __restrict__ wT,
                                                unsigned short* __restrict__ Qb,
                                                unsigned short* __restrict__ Kb,
                                                unsigned short* __restrict__ Vb) {
    const int bid = blockIdx.x;
    const int xcd = bid & 7, idx = bid >> 3;   // idx in [0,192)
    const int mt  = xcd * 16 + idx / 12;       // 128 M-tiles, 16 per XCD
    const int nt  = idx % 12;
    const int m0 = mt * 128, n0 = nt * 128;

    f32x4 acc[4][4];
    gemm_core_128(xb, wT, 512, m0, n0, acc);
    const int lane = threadIdx.x & 63, wv = threadIdx.x >> 6;
    const int wm = (wv >> 1) * 64, wn = (wv & 1) * 64;
    const int l15 = lane & 15, l16 = lane >> 4;
    #pragma unroll
    for (int j = 0; j < 4; ++j) {
        int col = n0 + wn + j * 16 + l15;
        int t = col >> 9;                      // 0=Q 1=K 2=V (uniform per block)
        int within = col & 511;
        int h = within >> 6, d = within & 63;
        unsigned short* dst = (t == 0) ? Qb : (t == 1) ? Kb : Vb;
        float scl = (t == 0) ? 0.125f : 1.0f;  // SCALE = 64^-0.5 folded into Q
        #pragma unroll
        for (int i = 0; i < 4; ++i)
            #pragma unroll
            for (int e = 0; e < 4; ++e) {
                int row = m0 + wm + i * 16 + (l16 << 2) + e;
                int b = row >> 9, n = row & 511;
                dst[(((size_t)b * 8 + h) * 512 + n) * 64 + d] = f2bf(acc[i][j][e] * scl);
            }
    }
}

// ---------- kernel 4: local-window flash attention (swapped-QK^T, 64-key half-tiles) ----------
// grid = 256 bh * 4 qtiles; block = 4 waves; each wave owns 32 q rows (one qh, half the w's).
__global__ __launch_bounds__(256, 4) void attn_kernel(const unsigned short* __restrict__ Qb,
                                                      const unsigned short* __restrict__ Kb,
                                                      const unsigned short* __restrict__ Vb,
                                                      unsigned short* __restrict__ Ob) {
    __shared__ unsigned short Ks[64 * 72];        // [key within half][d] pad to 72
    __shared__ unsigned short Vt[64 * 72];        // [d][key within half] pad to 72
    __shared__ unsigned short Ps[4 * 32 * 72];    // per-wave P tile [32 q][64 key] pad to 72

    const int bh = blockIdx.x >> 2;
    const int qt = blockIdx.x & 3;
    const int tid = threadIdx.x;
    const int lane = tid & 63;
    const int wv = tid >> 6;
    const int l15 = lane & 15, l16 = lane >> 4;
    const int b = bh >> 3, h = bh & 7;

    const unsigned short* Qp = Qb + (size_t)bh * 512 * 64;
    const unsigned short* Kp = Kb + (size_t)bh * 512 * 64;
    const unsigned short* Vp = Vb + (size_t)bh * 512 * 64;
    unsigned short* Pw = Ps + wv * 32 * 72;

    const int qrow0 = qt * 128 + wv * 32;
    const int qh = qrow0 >> 6;           // uniform per wave
    const int wq0 = qrow0 & 63;          // 0 or 32, uniform per wave
    const int dead_g = wq0 ? 0 : 3;      // fully-w-masked 16-key group per wave

    // per-lane w-mask bits: bit(qf*16 + g*4 + j) = |qw - kw| <= 5
    unsigned int wbits = 0;
    {
        int qw[2] = { wq0 + l15, wq0 + 16 + l15 };
        #pragma unroll
        for (int qf = 0; qf < 2; ++qf)
            #pragma unroll
            for (int g = 0; g < 4; ++g)
                #pragma unroll
                for (int j = 0; j < 4; ++j) {
                    int kw = g * 16 + (l16 << 2) + j;
                    int dw = qw[qf] - kw; dw = dw < 0 ? -dw : dw;
                    wbits |= (dw <= 5 ? 1u : 0u) << (qf * 16 + g * 4 + j);
                }
    }

    // Q B-fragments (q = qf*16+l15, k-contiguous) in registers; pre-scaled by SCALE
    bf16x8 bQ[2][2];
    #pragma unroll
    for (int qf = 0; qf < 2; ++qf)
        #pragma unroll
        for (int kf = 0; kf < 2; ++kf)
            bQ[qf][kf] = *(const bf16x8*)(const void*)(Qp + (size_t)(qrow0 + qf * 16 + l15) * 64 + kf * 32 + l16 * 8);

    f32x4 o[2][4];
    f32x4 zz = {0.f, 0.f, 0.f, 0.f};
    float mrow[2] = {-INFINITY, -INFINITY}, lrow[2] = {0.f, 0.f};
    #pragma unroll
    for (int qf = 0; qf < 2; ++qf)
        #pragma unroll
        for (int df = 0; df < 4; ++df) o[qf][df] = zz;

    for (int kh = 0; kh < 8; ++kh) {
        // block-level skip (uniform): kh in [2qt-3, 2qt+4]
        int dlo = kh - 2 * qt;
        if (dlo < -3 || dlo > 4) continue;
        __syncthreads();
        // stage K half-tile [64 keys][64 d] (vector LDS stores)
        #pragma unroll
        for (int c = 0; c < 2; ++c) {
            int flat16 = c * 256 + tid;
            int key = flat16 >> 3, dk = (flat16 & 7) * 8;
            *(uint4*)(void*)(Ks + key * 72 + dk) = *(const uint4*)(const void*)(Kp + ((size_t)(kh * 64 + key) * 64 + dk));
        }
        // stage V transposed: Vt[d][key]
        #pragma unroll
        for (int c = 0; c < 2; ++c) {
            int flat16 = c * 256 + tid;
            int key = flat16 & 63, d8 = flat16 >> 6;     // d8 in [0,8)
            union { uint4 v; unsigned short s[8]; } t;
            t.v = *(const uint4*)(const void*)(Vp + ((size_t)(kh * 64 + key) * 64 + d8 * 8));
            #pragma unroll
            for (int e = 0; e < 8; ++e) Vt[(d8 * 8 + e) * 72 + key] = t.s[e];
        }
        __syncthreads();

        int adq = qh - kh; adq = adq < 0 ? -adq : adq;
        if (adq > 3) continue;           // wave-uniform skip; no barriers below

        // S^T = K . Q^T : D[key = g*16 + l16*4 + j][q = qf*16 + l15]
        f32x4 s[2][4];
        #pragma unroll
        for (int qf = 0; qf < 2; ++qf)
            #pragma unroll
            for (int g = 0; g < 4; ++g) s[qf][g] = zz;
        #pragma unroll
        for (int g = 0; g < 4; ++g) {
            if (g == dead_g) continue;   // wave-uniform
            bf16x8 aK0 = *(const bf16x8*)(const void*)(Ks + (g * 16 + l15) * 72 + 0  + l16 * 8);
            bf16x8 aK1 = *(const bf16x8*)(const void*)(Ks + (g * 16 + l15) * 72 + 32 + l16 * 8);
            #pragma unroll
            for (int qf = 0; qf < 2; ++qf) {
                s[qf][g] = __builtin_amdgcn_mfma_f32_16x16x32_bf16(aK0, bQ[qf][0], s[qf][g], 0, 0, 0);
                s[qf][g] = __builtin_amdgcn_mfma_f32_16x16x32_bf16(aK1, bQ[qf][1], s[qf][g], 0, 0, 0);
            }
        }

        // w-mask + per-q running max (q is lane-local: q = qf*16+l15)
        float tmax[2] = {-1e30f, -1e30f};
        #pragma unroll
        for (int qf = 0; qf < 2; ++qf) {
            #pragma unroll
            for (int g = 0; g < 4; ++g) {
                if (g == dead_g) continue;
                #pragma unroll
                for (int j = 0; j < 4; ++j) {
                    float v = ((wbits >> (qf * 16 + g * 4 + j)) & 1u) ? s[qf][g][j] : -1e30f;
                    s[qf][g][j] = v;
                    tmax[qf] = fmaxf(tmax[qf], v);
                }
            }
            float t = tmax[qf];
            t = fmaxf(t, __shfl_xor(t, 16));
            t = fmaxf(t, __shfl_xor(t, 32));
            tmax[qf] = t;
        }

        // online-softmax update + O rescale (o rows live at q = qf*16 + l16*4 + j)
        #pragma unroll
        for (int qf = 0; qf < 2; ++qf) {
            float mnew = fmaxf(mrow[qf], tmax[qf]);
            float fs = __expf(mrow[qf] - mnew);
            mrow[qf] = mnew;
            lrow[qf] *= fs;
            #pragma unroll
            for (int j = 0; j < 4; ++j) {
                float fso = __shfl(fs, (l16 << 2) + j);
                #pragma unroll
                for (int df = 0; df < 4; ++df) o[qf][df][j] *= fso;
            }
        }

        // P = exp(S - m): pack pairs to bf16, b64 write into per-wave LDS; row sums
        #pragma unroll
        for (int qf = 0; qf < 2; ++qf) {
            float lsum = 0.f;
            #pragma unroll
            for (int g = 0; g < 4; ++g) {
                unsigned int lo, hi;
                if (g == dead_g) {
                    lo = 0u; hi = 0u;
                } else {
                    float e0 = __expf(s[qf][g][0] - mrow[qf]);
                    float e1 = __expf(s[qf][g][1] - mrow[qf]);
                    float e2 = __expf(s[qf][g][2] - mrow[qf]);
                    float e3 = __expf(s[qf][g][3] - mrow[qf]);
                    lsum += (e0 + e1) + (e2 + e3);
                    asm("v_cvt_pk_bf16_f32 %0, %1, %2" : "=v"(lo) : "v"(e0), "v"(e1));
                    asm("v_cvt_pk_bf16_f32 %0, %1, %2" : "=v"(hi) : "v"(e2), "v"(e3));
                }
                uint2 w; w.x = lo; w.y = hi;
                *(uint2*)(void*)(Pw + (qf * 16 + l15) * 72 + g * 16 + (l16 << 2)) = w;
            }
            float t = lsum;
            t += __shfl_xor(t, 16);
            t += __shfl_xor(t, 32);
            lrow[qf] += t;
        }
        asm volatile("" ::: "memory");   // order P writes before fragment reads (same wave, DS in-order)

        // O += P V  (A = P[q][k], B = V^T[d][k])
        #pragma unroll
        for (int kf = 0; kf < 2; ++kf) {
            bf16x8 aP0 = *(const bf16x8*)(const void*)(Pw + (0 * 16 + l15) * 72 + kf * 32 + l16 * 8);
            bf16x8 aP1 = *(const bf16x8*)(const void*)(Pw + (1 * 16 + l15) * 72 + kf * 32 + l16 * 8);
            #pragma unroll
            for (int df = 0; df < 4; ++df) {
                bf16x8 bV = *(const bf16x8*)(const void*)(Vt + (df * 16 + l15) * 72 + kf * 32 + l16 * 8);
                o[0][df] = __builtin_amdgcn_mfma_f32_16x16x32_bf16(aP0, bV, o[0][df], 0, 0, 0);
                o[1][df] = __builtin_amdgcn_mfma_f32_16x16x32_bf16(aP1, bV, o[1][df], 0, 0, 0);
            }
        }
    }

    // epilogue: O /= l, write bf16 [b][n][h*64+d]; o rows at q = qf*16 + l16*4 + j
    #pragma unroll
    for (int qf = 0; qf < 2; ++qf) {
        float linv = 1.0f / lrow[qf];
        #pragma unroll
        for (int j = 0; j < 4; ++j) {
            float lj = __shfl(linv, (l16 << 2) + j);
            int q = qrow0 + qf * 16 + (l16 << 2) + j;
            size_t base = ((size_t)b * 512 + q) * 512 + h * 64;
            #pragma unroll
            for (int df = 0; df < 4; ++df)
                Ob[base + df * 16 + l15] = f2bf(o[qf][df][j] * lj);
        }
    }
}

// ---------- kernel 5: projection GEMM (R2 core) + XCD swizzle + bias -> fp32 out ----------
// 512 blocks = 128 M-tiles x 4 N-tiles; 512 % 8 == 0 -> 16 M-tiles per XCD.
__global__ __launch_bounds__(256) void gemm_proj(const unsigned short* __restrict__ Ab,
                                                 const unsigned short* __restrict__ wT,
                                                 const float* __restrict__ bias,
                                                 float* __restrict__ out) {
    const int bid = blockIdx.x;
    const int xcd = bid & 7, idx = bid >> 3;   // idx in [0,64)
    const int mt  = xcd * 16 + idx / 4;
    const int nt  = idx % 4;
    const int m0 = mt * 128, n0 = nt * 128;

    f32x4 acc[4][4];
    gemm_core_128(Ab, wT, 512, m0, n0, acc);
    const int lane = threadIdx.x & 63, wv = threadIdx.x >> 6;
    const int wm = (wv >> 1) * 64, wn = (wv & 1) * 64;
    const int l15 = lane & 15, l16 = lane >> 4;
    #pragma unroll
    for (int j = 0; j < 4; ++j) {
        int col = n0 + wn + j * 16 + l15;
        float bb = bias[col];
        #pragma unroll
        for (int i = 0; i < 4; ++i)
            #pragma unroll
            for (int e = 0; e < 4; ++e) {
                int row = m0 + wm + i * 16 + (l16 << 2) + e;
                out[(size_t)row * 512 + col] = acc[i][j][e] + bb;
            }
    }
}

// ---------- launch ----------
extern "C" void kernel_launch(void* const* d_in, const int* in_sizes, int n_in,
                              void* d_out, int out_size, void* d_ws, size_t ws_size,
                              hipStream_t stream) {
    const float* x      = (const float*)d_in[0];   // [32,512,512]
    const float* w_qkv  = (const float*)d_in[1];   // [512,1536]
    const float* w_proj = (const float*)d_in[2];   // [512,512]
    const float* b_proj = (const float*)d_in[3];   // [512]
    // d_in[4] (mask) is reproduced analytically in-kernel.
    float* out = (float*)d_out;

    char* ws = (char*)d_ws;
    unsigned short* xb     = (unsigned short*)(ws);                 // 16 MB (reused as Ob)
    unsigned short* wqkvT  = (unsigned short*)(ws + 16777216);      // 1.5 MB
    unsigned short* wprojT = (unsigned short*)(ws + 18350080);      // 0.5 MB
    unsigned short* Qb     = (unsigned short*)(ws + 18874368);      // 16 MB
    unsigned short* Kb     = (unsigned short*)(ws + 35651584);      // 16 MB
    unsigned short* Vb     = (unsigned short*)(ws + 52428800);      // 16 MB
    unsigned short* Ob     = xb;  // xb dead after gemm_qkv; alias for attn output

    cvt_f32_bf16<<<4096, 256, 0, stream>>>((const float4*)x, (uint4*)xb, 1048576);
    transpose_cvt<<<dim3(48, 16), dim3(32, 8), 0, stream>>>(w_qkv, wqkvT, 512, 1536);
    transpose_cvt<<<dim3(16, 16), dim3(32, 8), 0, stream>>>(w_proj, wprojT, 512, 512);
    gemm_qkv<<<1536, 256, 0, stream>>>(xb, wqkvT, Qb, Kb, Vb);
    attn_kernel<<<1024, 256, 0, stream>>>(Qb, Kb, Vb, Ob);
    gemm_proj<<<512, 256, 0, stream>>>(Ob, wprojT, b_proj, out);
}